// Round 2
// baseline (235.108 us; speedup 1.0000x reference)
//
#include <hip/hip_runtime.h>

// IDWT 2D (Haar-style 2x2 filter bank), but NOTE the reference's output layout:
//   y = einsum('kab,kncij->ncijab', f, sub).reshape(B, C, 2H, 2W)
// The reshape is a raw row-major flatten of (i,j,a,b) -> (2H,2W), NOT a
// pixel-shuffle. Flat offset within an (n,c) plane:
//   i*(4W) + j*4 + a*2 + b
// i.e. each input pixel (i,j) yields 4 CONTIGUOUS output floats (ab=0..3).
//
// x: (B=8, 4*C=256, H=128, W=128) f32; filters: (4,1,2,2) f32
// out flat: nc*(4*H*W) + i*4W + j*4 + ab, value = sum_k f[k,ab]*x[n,k*C+c,i,j]
// Memory-bound: 134 MB read + 134 MB write -> ~43 us floor at 6.3 TB/s.

constexpr int B  = 8;
constexpr int C  = 64;   // C4/4
constexpr int H  = 128;
constexpr int W  = 128;
constexpr int W4 = W / 4;                        // 32 float4-groups per row
constexpr long PLANE_IN   = (long)H * W;         // 16384
constexpr long SUB_STRIDE = (long)C * PLANE_IN;  // 1,048,576 (one subband block)
constexpr long PLANE_OUT  = 4L * PLANE_IN;       // 65536 floats per (n,c) plane

__global__ __launch_bounds__(256) void idwt2d_kernel(
    const float* __restrict__ x,
    const float* __restrict__ f,
    float* __restrict__ out)
{
    // One thread handles 4 consecutive j columns of one (n,c,i) row.
    long tid = (long)blockIdx.x * blockDim.x + threadIdx.x;
    int jv = (int)(tid % W4);
    long t  = tid / W4;
    int i   = (int)(t % H);
    long nc = t / H;            // n*C + c, 0..511
    int c   = (int)(nc % C);
    int n   = (int)(nc / C);

    // Filters: wave-uniform scalar loads (broadcast). f[k*4 + a*2 + b]
    float fv[4][4];
#pragma unroll
    for (int k = 0; k < 4; ++k)
#pragma unroll
        for (int ab = 0; ab < 4; ++ab)
            fv[k][ab] = f[k * 4 + ab];

    const long base = ((long)(n * 4 * C + c)) * PLANE_IN + (long)i * W + (long)jv * 4;

    // Load 4 subband float4s (coalesced 16B/lane)
    float vv[4][4]; // [k][element]
#pragma unroll
    for (int k = 0; k < 4; ++k) {
        float4 t4 = *(const float4*)(x + base + (long)k * SUB_STRIDE);
        vv[k][0] = t4.x; vv[k][1] = t4.y; vv[k][2] = t4.z; vv[k][3] = t4.w;
    }

    // o[e][ab]: output for input column element e (j = jv*4+e), tap ab = a*2+b
    float o[4][4];
#pragma unroll
    for (int e = 0; e < 4; ++e) {
#pragma unroll
        for (int ab = 0; ab < 4; ++ab) {
            float acc = fv[0][ab] * vv[0][e];
#pragma unroll
            for (int k = 1; k < 4; ++k)
                acc += fv[k][ab] * vv[k][e];
            o[e][ab] = acc;
        }
    }

    // 16 contiguous output floats: offset = nc*PLANE_OUT + i*4W + jv*16
    const long outBase = nc * PLANE_OUT + (long)i * (4 * W) + (long)jv * 16;

#pragma unroll
    for (int e = 0; e < 4; ++e) {
        float4 r = make_float4(o[e][0], o[e][1], o[e][2], o[e][3]);
        *(float4*)(out + outBase + e * 4) = r;
    }
}

extern "C" void kernel_launch(void* const* d_in, const int* in_sizes, int n_in,
                              void* d_out, int out_size, void* d_ws, size_t ws_size,
                              hipStream_t stream)
{
    const float* x   = (const float*)d_in[0];
    const float* flt = (const float*)d_in[1];
    float* out       = (float*)d_out;

    // Total threads: B*C*H*(W/4) = 8*64*128*32 = 2,097,152 -> 8192 blocks x 256
    const long total = (long)B * C * H * W4;
    const int block = 256;
    const int grid = (int)((total + block - 1) / block);
    idwt2d_kernel<<<grid, block, 0, stream>>>(x, flt, out);
}

// Round 4
// 225.125 us; speedup vs baseline: 1.0443x; 1.0443x over previous
//
#include <hip/hip_runtime.h>

// IDWT 2D (Haar-style 2x2 filter bank). Reference output layout is a raw
// reshape of (B,C,H,W,2,2) -> (B,C,2H,2W): each input pixel (i,j) yields 4
// CONTIGUOUS output floats at nc*65536 + i*512 + j*4 + ab.
//
// R3 -> R4: same as R3 (one thread per input pixel; 4 coalesced dword loads,
// one contiguous dwordx4 nt-store) but with a native ext_vector_type for the
// nontemporal builtin (HIP's float4 class type is rejected by it).

typedef float floatx4 __attribute__((ext_vector_type(4)));

constexpr int B  = 8;
constexpr int C  = 64;   // C4/4
constexpr int H  = 128;
constexpr int W  = 128;
constexpr long PLANE_IN   = (long)H * W;         // 16384
constexpr long SUB_STRIDE = (long)C * PLANE_IN;  // 1,048,576 (one subband block)
constexpr long PLANE_OUT  = 4L * PLANE_IN;       // 65536 floats per (n,c) plane

__global__ __launch_bounds__(256) void idwt2d_kernel(
    const float* __restrict__ x,
    const float* __restrict__ f,
    float* __restrict__ out)
{
    // One thread per input pixel (n,c,i,j) -> one output float4.
    long tid = (long)blockIdx.x * blockDim.x + threadIdx.x;
    int j  = (int)(tid & (W - 1));          // W=128
    int i  = (int)((tid >> 7) & (H - 1));   // H=128
    long nc = tid >> 14;                    // n*C + c, 0..511
    int c   = (int)(nc & (C - 1));
    int n   = (int)(nc >> 6);

    // Filters: wave-uniform scalar loads (broadcast). f[k*4 + a*2 + b]
    float fv[4][4];
#pragma unroll
    for (int k = 0; k < 4; ++k)
#pragma unroll
        for (int ab = 0; ab < 4; ++ab)
            fv[k][ab] = f[k * 4 + ab];

    const long base = ((long)(n * 4 * C + c)) * PLANE_IN + (long)i * W + j;

    // 4 coalesced scalar loads (one per subband), lane stride 4 B.
    float v[4];
#pragma unroll
    for (int k = 0; k < 4; ++k)
        v[k] = x[base + (long)k * SUB_STRIDE];

    float o[4];
#pragma unroll
    for (int ab = 0; ab < 4; ++ab) {
        float acc = fv[0][ab] * v[0];
#pragma unroll
        for (int k = 1; k < 4; ++k)
            acc += fv[k][ab] * v[k];
        o[ab] = acc;
    }

    // One contiguous float4 store per thread (lane stride 16 B).
    // Non-temporal: output is never re-read; keep the input resident in L3.
    const long outOff = nc * PLANE_OUT + (long)i * (4 * W) + (long)j * 4;
    floatx4 r = { o[0], o[1], o[2], o[3] };
    __builtin_nontemporal_store(r, (floatx4*)(out + outOff));
}

extern "C" void kernel_launch(void* const* d_in, const int* in_sizes, int n_in,
                              void* d_out, int out_size, void* d_ws, size_t ws_size,
                              hipStream_t stream)
{
    const float* x   = (const float*)d_in[0];
    const float* flt = (const float*)d_in[1];
    float* out       = (float*)d_out;

    // Total threads: B*C*H*W = 8,388,608 -> 32768 blocks x 256
    const long total = (long)B * C * H * W;
    const int block = 256;
    const int grid = (int)((total + block - 1) / block);
    idwt2d_kernel<<<grid, block, 0, stream>>>(x, flt, out);
}